// Round 1
// baseline (2207.082 us; speedup 1.0000x reference)
//
#include <hip/hip_runtime.h>

// int4-grouped-quant GEMM: C[M,N] = A[M,K](fp32) @ dequant(Wq[K/2,N] int4-packed)
// dequant: W[k,n] = (nib(k,n) - zp[k/128,n]) * scale[k/128,n]
// Strategy: bf16 MFMA (16x16x32), 128x128 tile, BK=64, LDS-staged A (fp32->bf16)
// and B (on-the-fly dequant -> bf16). 4 waves per block, each wave 64x64 (4x4 MFMAs).

constexpr int M = 8192;
constexpr int K = 4096;
constexpr int N = 11008;

constexpr int BM = 128;
constexpr int BN = 128;
constexpr int BK = 64;

typedef short v8s __attribute__((ext_vector_type(8)));
typedef float v4f __attribute__((ext_vector_type(4)));

// round-to-nearest-even fp32 -> bf16, packed pair into one u32
__device__ __forceinline__ unsigned pack_bf16(float lo, float hi) {
    unsigned a = __builtin_bit_cast(unsigned, lo);
    a += 0x7FFFu + ((a >> 16) & 1u);
    unsigned b = __builtin_bit_cast(unsigned, hi);
    b += 0x7FFFu + ((b >> 16) & 1u);
    return (a >> 16) | (b & 0xFFFF0000u);
}

__global__ __launch_bounds__(256) void qgemm_kernel(
    const float* __restrict__ A,
    const int*   __restrict__ Wq,
    const float* __restrict__ scale,
    const int*   __restrict__ zp,
    float*       __restrict__ C)
{
    // LDS layout: [k-chunk (8 wide)][row][8] -> every fragment read is ds_read_b128
    __shared__ unsigned short sA[(BK / 8) * BM * 8];   // 16 KiB
    __shared__ unsigned short sB[(BK / 8) * BN * 8];   // 16 KiB

    const int t  = threadIdx.x;
    const int m0 = blockIdx.x * BM;
    const int n0 = blockIdx.y * BN;

    const int lane = t & 63;
    const int wave = t >> 6;
    const int wm   = (wave & 1) * 64;   // wave's m offset in tile
    const int wn   = (wave >> 1) * 64;  // wave's n offset in tile
    const int l16  = lane & 15;
    const int quad = lane >> 4;

    // B staging mapping: 128 n-columns x 2 row-groups
    const int bn  = t & 127;
    const int brg = t >> 7;

    v4f acc[4][4];
    #pragma unroll
    for (int i = 0; i < 4; ++i)
        #pragma unroll
        for (int j = 0; j < 4; ++j)
            acc[i][j] = (v4f){0.f, 0.f, 0.f, 0.f};

    for (int kt = 0; kt < K / BK; ++kt) {
        const int k0 = kt * BK;
        const int gq = k0 >> 7;  // quant group (GS=128); BK=64 tile never straddles
        const float sc = scale[gq * N + n0 + bn];
        const float zs = -sc * (float)zp[gq * N + n0 + bn];

        __syncthreads();  // previous tile fully consumed before overwrite

        // ---- stage A: 128 x 64 fp32 -> bf16 ----
        // 1024 units of 8 consecutive k; 4 per thread
        #pragma unroll
        for (int p = 0; p < 4; ++p) {
            int idx = t + p * 256;
            int m = idx >> 3;
            int c = idx & 7;
            const float* src = A + (size_t)(m0 + m) * K + k0 + c * 8;
            float4 f0 = *reinterpret_cast<const float4*>(src);
            float4 f1 = *reinterpret_cast<const float4*>(src + 4);
            uint4 w;
            w.x = pack_bf16(f0.x, f0.y);
            w.y = pack_bf16(f0.z, f0.w);
            w.z = pack_bf16(f1.x, f1.y);
            w.w = pack_bf16(f1.z, f1.w);
            *reinterpret_cast<uint4*>(&sA[(c * BM + m) * 8]) = w;
        }

        // ---- stage B: 32 packed rows x 128 n -> dequant -> bf16 ----
        // thread covers chunk g (8 k = 4 packed rows) at column bn
        #pragma unroll
        for (int p = 0; p < 4; ++p) {
            int g = brg + p * 2;  // 0..7
            const int* src = Wq + (size_t)((k0 >> 1) + g * 4) * N + n0 + bn;
            unsigned q0 = (unsigned)src[0];
            unsigned q1 = (unsigned)src[N];
            unsigned q2 = (unsigned)src[2 * N];
            unsigned q3 = (unsigned)src[3 * N];
            uint4 o;
            o.x = pack_bf16(fmaf((float)(q0 & 15u), sc, zs),
                            fmaf((float)((q0 >> 4) & 15u), sc, zs));
            o.y = pack_bf16(fmaf((float)(q1 & 15u), sc, zs),
                            fmaf((float)((q1 >> 4) & 15u), sc, zs));
            o.z = pack_bf16(fmaf((float)(q2 & 15u), sc, zs),
                            fmaf((float)((q2 >> 4) & 15u), sc, zs));
            o.w = pack_bf16(fmaf((float)(q3 & 15u), sc, zs),
                            fmaf((float)((q3 >> 4) & 15u), sc, zs));
            *reinterpret_cast<uint4*>(&sB[(g * BN + bn) * 8]) = o;
        }

        __syncthreads();

        // ---- compute: 2 k-windows of 32, 16 MFMAs each per wave ----
        #pragma unroll
        for (int kw = 0; kw < 2; ++kw) {
            int cb = kw * 4 + quad;  // this lane's k-chunk
            v8s af[4], bfr[4];
            #pragma unroll
            for (int i = 0; i < 4; ++i)
                af[i] = *reinterpret_cast<const v8s*>(&sA[(cb * BM + wm + i * 16 + l16) * 8]);
            #pragma unroll
            for (int j = 0; j < 4; ++j)
                bfr[j] = *reinterpret_cast<const v8s*>(&sB[(cb * BN + wn + j * 16 + l16) * 8]);
            #pragma unroll
            for (int i = 0; i < 4; ++i)
                #pragma unroll
                for (int j = 0; j < 4; ++j)
                    acc[i][j] = __builtin_amdgcn_mfma_f32_16x16x32_bf16(
                        af[i], bfr[j], acc[i][j], 0, 0, 0);
        }
    }

    // ---- epilogue: C/D layout col=lane&15, row=quad*4+reg ----
    #pragma unroll
    for (int i = 0; i < 4; ++i) {
        int rbase = m0 + wm + i * 16 + quad * 4;
        #pragma unroll
        for (int j = 0; j < 4; ++j) {
            int col = n0 + wn + j * 16 + l16;
            #pragma unroll
            for (int r = 0; r < 4; ++r)
                C[(size_t)(rbase + r) * N + col] = acc[i][j][r];
        }
    }
}

extern "C" void kernel_launch(void* const* d_in, const int* in_sizes, int n_in,
                              void* d_out, int out_size, void* d_ws, size_t ws_size,
                              hipStream_t stream) {
    const float* A     = (const float*)d_in[0];
    const int*   Wq    = (const int*)d_in[1];
    const float* scale = (const float*)d_in[2];
    const int*   zp    = (const int*)d_in[3];
    float*       C     = (float*)d_out;

    dim3 grid(M / BM, N / BN);  // 64 x 86, exact fit
    qgemm_kernel<<<grid, dim3(256), 0, stream>>>(A, Wq, scale, zp, C);
}